// Round 7
// baseline (167.056 us; speedup 1.0000x reference)
//
#include <hip/hip_runtime.h>

// ============================================================================
// ROUND 7 = DECOMPOSITION PROBE. Identical kernels to round 6, but
// plane_score_kernel is launched 9x (idempotent -> same output). dur_us then
// decomposes the 46us of invisible kernel time: P = (dur - 51.3)/8.
// ============================================================================

#define B 64
#define N 1024
#define G 256
#define H 512

// exp(-50*d^2) = 2^(-72.134752*d^2); pre-scale plane coeffs by sqrt(72.134752)
#define S_SCALE 8.4932183f
#define INV_S   (1.0f / S_SCALE)

__device__ __forceinline__ float exp2_fast(float x) {
#if __has_builtin(__builtin_amdgcn_exp2f)
    return __builtin_amdgcn_exp2f(x);   // raw v_exp_f32
#else
    return __expf(x * 0.69314718056f);  // e^(x ln2) = 2^x
#endif
}

// ---------------------------------------------------------------------------
// Kernel 1: stable top-k (k=G=256) of pt_weight per batch via O(N^2) ranking.
// ---------------------------------------------------------------------------
#define TKB 4  // blocks per batch

__global__ __launch_bounds__(256) void topk_gather_kernel(
    const float* __restrict__ pts,        // (B,3,N)
    const float* __restrict__ pt_weight,  // (B,N)
    float* __restrict__ out_gpts)         // (B,G,3)
{
    const int b = blockIdx.x / TKB;
    const int q = blockIdx.x % TKB;

    __shared__ float w[N];
    ((float4*)w)[threadIdx.x] = ((const float4*)(pt_weight + (size_t)b * N))[threadIdx.x];
    __syncthreads();

    const int i = q * 256 + threadIdx.x;
    const float wi = w[i];

    int rank = 0;
#pragma unroll 8
    for (int j = 0; j < N; j += 4) {
        const float4 wj = *(const float4*)(w + j);  // broadcast LDS read
        rank += (wj.x > wi) || (wj.x == wi && (j + 0) < i);
        rank += (wj.y > wi) || (wj.y == wi && (j + 1) < i);
        rank += (wj.z > wi) || (wj.z == wi && (j + 2) < i);
        rank += (wj.w > wi) || (wj.w == wi && (j + 3) < i);
    }

    if (rank < G) {
        float* dst = out_gpts + ((size_t)b * G + rank) * 3;
        dst[0] = pts[b * 3 * N + 0 * N + i];
        dst[1] = pts[b * 3 * N + 1 * N + i];
        dst[2] = pts[b * 3 * N + 2 * N + i];
    }
}

// ---------------------------------------------------------------------------
// Kernel 2: plane + score + loss. (Probed 9x this round.)
// ---------------------------------------------------------------------------
__global__ __launch_bounds__(256) void plane_score_kernel(
    const float* __restrict__ pts,      // (B,3,N)
    const float* __restrict__ target,   // (B,3)
    const int* __restrict__ sel_idx,    // (B,H,3)
    const float* __restrict__ gpts,     // (B,G,3) [in d_out, from kernel 1]
    float* __restrict__ score,          // ws (B,H)
    float* __restrict__ loss,           // ws (B,H)
    float* __restrict__ normals)        // ws (B,H,3)
{
    __shared__ float sp[3 * N];   // 12 KB
    __shared__ float gp[3 * G];   // 3 KB
    const int blk = blockIdx.x;
    const int tid = threadIdx.x;
    const int b   = blk >> 4;   // 64 batches
    const int hg  = blk & 15;   // 16 hypothesis-groups per batch
    const int wave = tid >> 6;
    const int lane = tid & 63;

    {
        const float4* ps = (const float4*)(pts + (size_t)b * 3 * N);
        float4* spv = (float4*)sp;
        spv[tid]       = ps[tid];
        spv[tid + 256] = ps[tid + 256];
        spv[tid + 512] = ps[tid + 512];
        if (tid < 192)
            ((float4*)gp)[tid] = ((const float4*)(gpts + (size_t)b * 3 * G))[tid];
    }
    __syncthreads();

    const int h0 = (hg << 5) + (wave << 3);  // 32 hyps/block, 8/wave
    float nx[8], ny[8], nz[8], pd[8], acc[8];

    #pragma unroll
    for (int hh = 0; hh < 8; ++hh) {
        const int* si = sel_idx + ((size_t)b * H + h0 + hh) * 3;
        const int g0 = si[0] * 3, g1 = si[1] * 3, g2 = si[2] * 3;
        const float p0x = gp[g0], p0y = gp[g0 + 1], p0z = gp[g0 + 2];
        const float p1x = gp[g1], p1y = gp[g1 + 1], p1z = gp[g1 + 2];
        const float p2x = gp[g2], p2y = gp[g2 + 1], p2z = gp[g2 + 2];
        const float e1x = p1x - p0x, e1y = p1y - p0y, e1z = p1z - p0z;
        const float e2x = p2x - p0x, e2y = p2y - p0y, e2z = p2z - p0z;
        float x = e1y * e2z - e1z * e2y;
        float y = e1z * e2x - e1x * e2z;
        float z = e1x * e2y - e1y * e2x;
        float d = -(x * p0x + y * p0y + z * p0z);
        if (x == 0.f && y == 0.f && z == 0.f && d == 0.f) { x = y = z = d = 1.f; }
        const float ns = S_SCALE / sqrtf(x * x + y * y + z * z);
        nx[hh] = x * ns; ny[hh] = y * ns; nz[hh] = z * ns; pd[hh] = d * ns;
        acc[hh] = 0.f;
    }

    #pragma unroll 4
    for (int k = 0; k < N / 64; ++k) {
        const int n = lane + (k << 6);
        const float px = sp[n], py = sp[N + n], pz = sp[2 * N + n];
        #pragma unroll
        for (int hh = 0; hh < 8; ++hh) {
            const float u = fmaf(nx[hh], px, fmaf(ny[hh], py, fmaf(nz[hh], pz, pd[hh])));
            acc[hh] += exp2_fast(-(u * u));  // neg folds into v_exp src modifier
        }
    }

    const float tx = target[b * 3 + 0], ty = target[b * 3 + 1], tz = target[b * 3 + 2];
    #pragma unroll
    for (int hh = 0; hh < 8; ++hh) {
        float a = acc[hh];
        #pragma unroll
        for (int off = 32; off; off >>= 1) a += __shfl_xor(a, off);
        if (lane == 0) {
            const float x = nx[hh] * INV_S, y = ny[hh] * INV_S, z = nz[hh] * INV_S;
            const float l1 = (x - tx) * (x - tx) + (y - ty) * (y - ty) + (z - tz) * (z - tz);
            const float l2 = (x + tx) * (x + tx) + (y + ty) * (y + ty) + (z + tz) * (z + tz);
            const int idx = b * H + h0 + hh;
            score[idx] = a;
            loss[idx] = fminf(l1, l2);
            normals[idx * 3 + 0] = x;
            normals[idx * 3 + 1] = y;
            normals[idx * 3 + 2] = z;
        }
    }
}

// ---------------------------------------------------------------------------
// Kernel 3: per batch finalize.
// ---------------------------------------------------------------------------
__global__ __launch_bounds__(256) void finalize_kernel(
    const float* __restrict__ score,    // (B,H)
    const float* __restrict__ loss,     // (B,H)
    const float* __restrict__ normals,  // (B,H,3)
    float* __restrict__ out)            // exp_loss(B)|top_loss(B)|pred(3B)|gpts...
{
    const int b = blockIdx.x;
    const int tid = threadIdx.x;
    const int wave = tid >> 6;
    const int lane = tid & 63;

    __shared__ float sv[4]; __shared__ int sidx[4];
    __shared__ float ssw[4], sswl[4];
    __shared__ float s_max; __shared__ int s_maxi;

    const float* sc = score + b * H;
    const float* ls = loss + b * H;
    const float s0 = sc[tid], s1 = sc[tid + 256];

    float v; int vi;
    if (s1 > s0) { v = s1; vi = tid + 256; } else { v = s0; vi = tid; }
    #pragma unroll
    for (int off = 32; off; off >>= 1) {
        const float v2 = __shfl_xor(v, off);
        const int i2 = __shfl_xor(vi, off);
        if (v2 > v || (v2 == v && i2 < vi)) { v = v2; vi = i2; }
    }
    if (lane == 0) { sv[wave] = v; sidx[wave] = vi; }
    __syncthreads();

    if (tid == 0) {
        float bv = sv[0]; int bi = sidx[0];
        #pragma unroll
        for (int k = 1; k < 4; ++k) {
            if (sv[k] > bv || (sv[k] == bv && sidx[k] < bi)) { bv = sv[k]; bi = sidx[k]; }
        }
        s_max = bv; s_maxi = bi;
    }
    __syncthreads();

    const float m = s_max;
    const float w0 = __expf(0.5f * (s0 - m)), w1 = __expf(0.5f * (s1 - m));
    float tw = w0 + w1;
    float twl = w0 * ls[tid] + w1 * ls[tid + 256];
    #pragma unroll
    for (int off = 32; off; off >>= 1) {
        tw += __shfl_xor(tw, off);
        twl += __shfl_xor(twl, off);
    }
    if (lane == 0) { ssw[wave] = tw; sswl[wave] = twl; }
    __syncthreads();

    if (tid == 0) {
        const float TW = ssw[0] + ssw[1] + ssw[2] + ssw[3];
        const float TWL = sswl[0] + sswl[1] + sswl[2] + sswl[3];
        const int mi = s_maxi;
        out[b] = TWL / TW;                               // exp_loss
        out[B + b] = ls[mi];                             // top_loss
        out[2 * B + b * 3 + 0] = normals[((size_t)b * H + mi) * 3 + 0];
        out[2 * B + b * 3 + 1] = normals[((size_t)b * H + mi) * 3 + 1];
        out[2 * B + b * 3 + 2] = normals[((size_t)b * H + mi) * 3 + 2];
    }
}

// ---------------------------------------------------------------------------
extern "C" void kernel_launch(void* const* d_in, const int* in_sizes, int n_in,
                              void* d_out, int out_size, void* d_ws, size_t ws_size,
                              hipStream_t stream) {
    const float* pts       = (const float*)d_in[0];  // (B,3,N)
    const float* target    = (const float*)d_in[1];  // (B,3)
    const float* pt_weight = (const float*)d_in[2];  // (B,N)
    const int*   sel_idx   = (const int*)d_in[3];    // (B,H,3)

    float* out = (float*)d_out;
    // layout: exp_loss[B] | top_loss[B] | pred[B*3] | gpts[B*G*3]
    float* out_gpts = out + 5 * B;

    float* ws      = (float*)d_ws;
    float* score   = ws;                      // B*H
    float* loss    = ws + B * H;              // B*H
    float* normals = ws + 2 * B * H;          // B*H*3

    topk_gather_kernel<<<B * TKB, 256, 0, stream>>>(pts, pt_weight, out_gpts);

    // PROBE: 9 identical idempotent launches; P = (dur_us - 51.3) / 8.
    for (int r = 0; r < 9; ++r) {
        plane_score_kernel<<<B * 16, 256, 0, stream>>>(pts, target, sel_idx, out_gpts,
                                                       score, loss, normals);
    }

    finalize_kernel<<<B, 256, 0, stream>>>(score, loss, normals, out);
}

// Round 8
// 81.689 us; speedup vs baseline: 2.0450x; 2.0450x over previous
//
#include <hip/hip_runtime.h>

#define B 64
#define N 1024
#define G 256
#define H 512

// exp(-50*d^2) = 2^(-72.134752*d^2); pre-scale plane coeffs by sqrt(72.134752)
#define S_SCALE 8.4932183f
#define INV_S   (1.0f / S_SCALE)

__device__ __forceinline__ float exp2_fast(float x) {
#if __has_builtin(__builtin_amdgcn_exp2f)
    return __builtin_amdgcn_exp2f(x);   // raw v_exp_f32
#else
    return __expf(x * 0.69314718056f);  // e^(x ln2) = 2^x
#endif
}

// ---------------------------------------------------------------------------
// Node A: stable top-k (k=G=256) of pt_weight per batch via O(N^2) ranking.
// 4 blocks per batch; thread ranks one element against all N via broadcast
// float4 LDS reads. rank_i = #{ j : w_j > w_i or (w_j == w_i and j < i) }
// == exact lax.top_k order (descending, ties -> lower index).
// ---------------------------------------------------------------------------
#define TKB 4  // blocks per batch

__global__ __launch_bounds__(256) void topk_gather_kernel(
    const float* __restrict__ pts,        // (B,3,N)
    const float* __restrict__ pt_weight,  // (B,N)
    float* __restrict__ out_gpts)         // (B,G,3)
{
    const int b = blockIdx.x / TKB;
    const int q = blockIdx.x % TKB;

    __shared__ float w[N];
    ((float4*)w)[threadIdx.x] = ((const float4*)(pt_weight + (size_t)b * N))[threadIdx.x];
    __syncthreads();

    const int i = q * 256 + threadIdx.x;
    const float wi = w[i];

    int rank = 0;
#pragma unroll 8
    for (int j = 0; j < N; j += 4) {
        const float4 wj = *(const float4*)(w + j);  // broadcast LDS read
        rank += (wj.x > wi) || (wj.x == wi && (j + 0) < i);
        rank += (wj.y > wi) || (wj.y == wi && (j + 1) < i);
        rank += (wj.z > wi) || (wj.z == wi && (j + 2) < i);
        rank += (wj.w > wi) || (wj.w == wi && (j + 3) < i);
    }

    if (rank < G) {
        float* dst = out_gpts + ((size_t)b * G + rank) * 3;
        dst[0] = pts[b * 3 * N + 0 * N + i];
        dst[1] = pts[b * 3 * N + 1 * N + i];
        dst[2] = pts[b * 3 * N + 2 * N + i];
    }
}

// ---------------------------------------------------------------------------
// Node B: one block per batch (1024 threads = 16 waves). Each wave computes
// 32 hypotheses (4 chunks of 8, register-resident: full unroll, rule #20),
// writes score/loss/normals to LDS, then the block finalizes in-LDS:
// argmax (tie -> first), stable softmax(0.5*score), exp_loss, top_loss, pred.
// No ws, no fences, no atomics — all communication is LDS + __syncthreads.
// ---------------------------------------------------------------------------
__global__ __launch_bounds__(1024) void plane_finalize_kernel(
    const float* __restrict__ pts,      // (B,3,N)
    const float* __restrict__ target,   // (B,3)
    const int* __restrict__ sel_idx,    // (B,H,3)
    float* __restrict__ out)            // exp_loss(B)|top_loss(B)|pred(3B)|gpts(B,G,3)
{
    __shared__ float sp[3 * N];      // 12 KB  pts[b], [c][n]
    __shared__ float gp[3 * G];      // 3 KB   gathered pts
    __shared__ float s_score[H];     // 2 KB
    __shared__ float s_loss[H];      // 2 KB
    __shared__ float s_norm[3 * H];  // 6 KB   [h*3+c]
    __shared__ float sv[16]; __shared__ int sidx[16];
    __shared__ float ssw[16], sswl[16];
    __shared__ float s_max; __shared__ int s_maxi;

    const int b   = blockIdx.x;
    const int tid = threadIdx.x;
    const int wave = tid >> 6;
    const int lane = tid & 63;
    const float* gpts = out + 5 * B;   // written by node A

    // ---------------- stage pts + gpts into LDS ----------------
    {
        const float4* ps = (const float4*)(pts + (size_t)b * 3 * N);
        if (tid < 768) ((float4*)sp)[tid] = ps[tid];
        else if (tid < 960) ((float4*)gp)[tid - 768] =
            ((const float4*)(gpts + (size_t)b * 3 * G))[tid - 768];
    }
    __syncthreads();

    const float tx = target[b * 3 + 0], ty = target[b * 3 + 1], tz = target[b * 3 + 2];

    // ---------------- plane + score + loss: 4 chunks x 8 hyps per wave ------
    for (int cc = 0; cc < 4; ++cc) {
        const int h0 = (wave << 5) + (cc << 3);   // 16 waves x 32 hyps
        float nx[8], ny[8], nz[8], pd[8], acc[8];

        #pragma unroll   // FULL unroll: hh must be compile-time (rule #20)
        for (int hh = 0; hh < 8; ++hh) {
            const int* si = sel_idx + ((size_t)b * H + h0 + hh) * 3;
            const int g0 = si[0] * 3, g1 = si[1] * 3, g2 = si[2] * 3;
            const float p0x = gp[g0], p0y = gp[g0 + 1], p0z = gp[g0 + 2];
            const float p1x = gp[g1], p1y = gp[g1 + 1], p1z = gp[g1 + 2];
            const float p2x = gp[g2], p2y = gp[g2 + 1], p2z = gp[g2 + 2];
            const float e1x = p1x - p0x, e1y = p1y - p0y, e1z = p1z - p0z;
            const float e2x = p2x - p0x, e2y = p2y - p0y, e2z = p2z - p0z;
            float x = e1y * e2z - e1z * e2y;
            float y = e1z * e2x - e1x * e2z;
            float z = e1x * e2y - e1y * e2x;
            float d = -(x * p0x + y * p0y + z * p0z);
            if (x == 0.f && y == 0.f && z == 0.f && d == 0.f) { x = y = z = d = 1.f; }
            const float ns = S_SCALE / sqrtf(x * x + y * y + z * z);
            nx[hh] = x * ns; ny[hh] = y * ns; nz[hh] = z * ns; pd[hh] = d * ns;
            acc[hh] = 0.f;
        }

        #pragma unroll 4
        for (int k = 0; k < N / 64; ++k) {
            const int n = lane + (k << 6);
            const float px = sp[n], py = sp[N + n], pz = sp[2 * N + n];
            #pragma unroll
            for (int hh = 0; hh < 8; ++hh) {
                const float u = fmaf(nx[hh], px, fmaf(ny[hh], py, fmaf(nz[hh], pz, pd[hh])));
                acc[hh] += exp2_fast(-(u * u));  // neg folds into v_exp src modifier
            }
        }

        #pragma unroll
        for (int hh = 0; hh < 8; ++hh) {
            float a = acc[hh];
            #pragma unroll
            for (int off = 32; off; off >>= 1) a += __shfl_xor(a, off);
            if (lane == 0) {
                const float x = nx[hh] * INV_S, y = ny[hh] * INV_S, z = nz[hh] * INV_S;
                const float l1 = (x - tx) * (x - tx) + (y - ty) * (y - ty) + (z - tz) * (z - tz);
                const float l2 = (x + tx) * (x + tx) + (y + ty) * (y + ty) + (z + tz) * (z + tz);
                const int h = h0 + hh;
                s_score[h] = a;
                s_loss[h] = fminf(l1, l2);
                s_norm[h * 3 + 0] = x;
                s_norm[h * 3 + 1] = y;
                s_norm[h * 3 + 2] = z;
            }
        }
    }
    __syncthreads();

    // ---------------- in-block finalize (threads 0..511 active) ----------------
    const bool act = (tid < H);
    float s = 0.f, l = 0.f;
    if (act) { s = s_score[tid]; l = s_loss[tid]; }

    if (act) {   // wave-uniform guard (waves 8-15 skip)
        float v = s; int vi = tid;
        #pragma unroll
        for (int off = 32; off; off >>= 1) {
            const float v2 = __shfl_xor(v, off);
            const int i2 = __shfl_xor(vi, off);
            if (v2 > v || (v2 == v && i2 < vi)) { v = v2; vi = i2; }
        }
        if (lane == 0) { sv[wave] = v; sidx[wave] = vi; }
    }
    __syncthreads();

    if (tid == 0) {
        float bv = sv[0]; int bi = sidx[0];
        #pragma unroll
        for (int k = 1; k < 8; ++k) {
            if (sv[k] > bv || (sv[k] == bv && sidx[k] < bi)) { bv = sv[k]; bi = sidx[k]; }
        }
        s_max = bv; s_maxi = bi;
    }
    __syncthreads();

    if (act) {
        const float m = s_max;
        float wgt = __expf(0.5f * (s - m));
        float wl = wgt * l;
        #pragma unroll
        for (int off = 32; off; off >>= 1) {
            wgt += __shfl_xor(wgt, off);
            wl += __shfl_xor(wl, off);
        }
        if (lane == 0) { ssw[wave] = wgt; sswl[wave] = wl; }
    }
    __syncthreads();

    if (tid == 0) {
        float TW = 0.f, TWL = 0.f;
        #pragma unroll
        for (int k = 0; k < 8; ++k) { TW += ssw[k]; TWL += sswl[k]; }
        const int mi = s_maxi;
        out[b] = TWL / TW;                      // exp_loss
        out[B + b] = s_loss[mi];                // top_loss
        out[2 * B + b * 3 + 0] = s_norm[mi * 3 + 0];
        out[2 * B + b * 3 + 1] = s_norm[mi * 3 + 1];
        out[2 * B + b * 3 + 2] = s_norm[mi * 3 + 2];
    }
}

// ---------------------------------------------------------------------------
extern "C" void kernel_launch(void* const* d_in, const int* in_sizes, int n_in,
                              void* d_out, int out_size, void* d_ws, size_t ws_size,
                              hipStream_t stream) {
    const float* pts       = (const float*)d_in[0];  // (B,3,N)
    const float* target    = (const float*)d_in[1];  // (B,3)
    const float* pt_weight = (const float*)d_in[2];  // (B,N)
    const int*   sel_idx   = (const int*)d_in[3];    // (B,H,3)

    float* out = (float*)d_out;
    // layout: exp_loss[B] | top_loss[B] | pred[B*3] | gpts[B*G*3]
    float* out_gpts = out + 5 * B;

    topk_gather_kernel<<<B * TKB, 256, 0, stream>>>(pts, pt_weight, out_gpts);
    plane_finalize_kernel<<<B, 1024, 0, stream>>>(pts, target, sel_idx, out);
}

// Round 9
// 33.545 us; speedup vs baseline: 4.9800x; 2.4352x over previous
//
#include <hip/hip_runtime.h>

#define B 64
#define N 1024
#define G 256
#define H 512

// exp(-50*d^2) = 2^(-72.134752*d^2); pre-scale plane coeffs by sqrt(72.134752)
#define S_SCALE 8.4932183f
#define INV_S   (1.0f / S_SCALE)

__device__ __forceinline__ float exp2_fast(float x) {
#if __has_builtin(__builtin_amdgcn_exp2f)
    return __builtin_amdgcn_exp2f(x);   // raw v_exp_f32
#else
    return __expf(x * 0.69314718056f);  // e^(x ln2) = 2^x
#endif
}

// ---------------------------------------------------------------------------
// Kernel 1: stable top-k (k=G=256) via O(N^2) ranking, j-split 4 ways.
// 4 blocks per batch x 1024 threads. Thread (e, p=tid>>8) computes the
// partial rank of element i = q*256+e over j in [p*256,(p+1)*256); partials
// summed in LDS. 16 waves/block = 4 waves/SIMD (vs r6's 1) hides LDS and
// compare-chain latency (r8 fit: topk was ~16us latency-bound at 1 wave/SIMD).
// rank semantics == lax.top_k: descending, ties -> lower original index.
// p < q: all j < i (ties count, >=); p > q: all j > i (>); p == q: mixed.
// ---------------------------------------------------------------------------
#define TKB 4  // blocks per batch

__global__ __launch_bounds__(1024) void topk_gather_kernel(
    const float* __restrict__ pts,        // (B,3,N)
    const float* __restrict__ pt_weight,  // (B,N)
    float* __restrict__ out_gpts)         // (B,G,3)
{
    const int b = blockIdx.x / TKB;
    const int q = blockIdx.x % TKB;
    const int tid = threadIdx.x;

    __shared__ float w[N];
    __shared__ int part[4][256];

    w[tid] = pt_weight[(size_t)b * N + tid];
    __syncthreads();

    const int e = tid & 255;
    const int p = tid >> 8;            // j-quarter (wave-uniform: 4 waves per p)
    const int i = (q << 8) + e;        // global element index
    const float wi = w[i];
    const float* wq = w + (p << 8);

    int r = 0;
    if (p < q) {            // all j < i: ties count
        #pragma unroll 8
        for (int j = 0; j < 256; j += 4) {
            const float4 wj = *(const float4*)(wq + j);
            r += (wj.x >= wi) + (wj.y >= wi) + (wj.z >= wi) + (wj.w >= wi);
        }
    } else if (p > q) {     // all j > i: ties don't count
        #pragma unroll 8
        for (int j = 0; j < 256; j += 4) {
            const float4 wj = *(const float4*)(wq + j);
            r += (wj.x > wi) + (wj.y > wi) + (wj.z > wi) + (wj.w > wi);
        }
    } else {                // mixed quarter: j and i in same 256-range
        const int j0 = p << 8;
        #pragma unroll 8
        for (int j = 0; j < 256; j += 4) {
            const float4 wj = *(const float4*)(wq + j);
            r += (wj.x > wi) || (wj.x == wi && (j0 + j + 0) < i);
            r += (wj.y > wi) || (wj.y == wi && (j0 + j + 1) < i);
            r += (wj.z > wi) || (wj.z == wi && (j0 + j + 2) < i);
            r += (wj.w > wi) || (wj.w == wi && (j0 + j + 3) < i);
        }
    }
    part[p][e] = r;
    __syncthreads();

    if (p == 0) {
        const int rank = part[0][e] + part[1][e] + part[2][e] + part[3][e];
        if (rank < G) {
            float* dst = out_gpts + ((size_t)b * G + rank) * 3;
            dst[0] = pts[b * 3 * N + 0 * N + i];
            dst[1] = pts[b * 3 * N + 1 * N + i];
            dst[2] = pts[b * 3 * N + 2 * N + i];
        }
    }
}

// ---------------------------------------------------------------------------
// Kernel 2: plane + score + loss (r6 version, proven ~5us at 1024 blocks).
// One block = one batch x 32 hypotheses; pts[b] (12KB) + gpts[b] (3KB) in LDS.
// Each wave evaluates 8 register-resident hypotheses per point-load.
// ---------------------------------------------------------------------------
__global__ __launch_bounds__(256) void plane_score_kernel(
    const float* __restrict__ pts,      // (B,3,N)
    const float* __restrict__ target,   // (B,3)
    const int* __restrict__ sel_idx,    // (B,H,3)
    const float* __restrict__ gpts,     // (B,G,3) [in d_out, from kernel 1]
    float* __restrict__ score,          // ws (B,H)
    float* __restrict__ loss,           // ws (B,H)
    float* __restrict__ normals)        // ws (B,H,3)
{
    __shared__ float sp[3 * N];   // 12 KB
    __shared__ float gp[3 * G];   // 3 KB
    const int blk = blockIdx.x;
    const int tid = threadIdx.x;
    const int b   = blk >> 4;   // 64 batches
    const int hg  = blk & 15;   // 16 hypothesis-groups per batch
    const int wave = tid >> 6;
    const int lane = tid & 63;

    {
        const float4* ps = (const float4*)(pts + (size_t)b * 3 * N);
        float4* spv = (float4*)sp;
        spv[tid]       = ps[tid];
        spv[tid + 256] = ps[tid + 256];
        spv[tid + 512] = ps[tid + 512];
        if (tid < 192)
            ((float4*)gp)[tid] = ((const float4*)(gpts + (size_t)b * 3 * G))[tid];
    }
    __syncthreads();

    const int h0 = (hg << 5) + (wave << 3);  // 32 hyps/block, 8/wave
    float nx[8], ny[8], nz[8], pd[8], acc[8];

    #pragma unroll   // FULL unroll: hh must be compile-time (rule #20)
    for (int hh = 0; hh < 8; ++hh) {
        const int* si = sel_idx + ((size_t)b * H + h0 + hh) * 3;
        const int g0 = si[0] * 3, g1 = si[1] * 3, g2 = si[2] * 3;
        const float p0x = gp[g0], p0y = gp[g0 + 1], p0z = gp[g0 + 2];
        const float p1x = gp[g1], p1y = gp[g1 + 1], p1z = gp[g1 + 2];
        const float p2x = gp[g2], p2y = gp[g2 + 1], p2z = gp[g2 + 2];
        const float e1x = p1x - p0x, e1y = p1y - p0y, e1z = p1z - p0z;
        const float e2x = p2x - p0x, e2y = p2y - p0y, e2z = p2z - p0z;
        float x = e1y * e2z - e1z * e2y;
        float y = e1z * e2x - e1x * e2z;
        float z = e1x * e2y - e1y * e2x;
        float d = -(x * p0x + y * p0y + z * p0z);
        if (x == 0.f && y == 0.f && z == 0.f && d == 0.f) { x = y = z = d = 1.f; }
        const float ns = S_SCALE / sqrtf(x * x + y * y + z * z);
        nx[hh] = x * ns; ny[hh] = y * ns; nz[hh] = z * ns; pd[hh] = d * ns;
        acc[hh] = 0.f;
    }

    #pragma unroll 4
    for (int k = 0; k < N / 64; ++k) {
        const int n = lane + (k << 6);
        const float px = sp[n], py = sp[N + n], pz = sp[2 * N + n];
        #pragma unroll
        for (int hh = 0; hh < 8; ++hh) {
            const float u = fmaf(nx[hh], px, fmaf(ny[hh], py, fmaf(nz[hh], pz, pd[hh])));
            acc[hh] += exp2_fast(-(u * u));  // neg folds into v_exp src modifier
        }
    }

    const float tx = target[b * 3 + 0], ty = target[b * 3 + 1], tz = target[b * 3 + 2];
    #pragma unroll
    for (int hh = 0; hh < 8; ++hh) {
        float a = acc[hh];
        #pragma unroll
        for (int off = 32; off; off >>= 1) a += __shfl_xor(a, off);
        if (lane == 0) {
            const float x = nx[hh] * INV_S, y = ny[hh] * INV_S, z = nz[hh] * INV_S;
            const float l1 = (x - tx) * (x - tx) + (y - ty) * (y - ty) + (z - tz) * (z - tz);
            const float l2 = (x + tx) * (x + tx) + (y + ty) * (y + ty) + (z + tz) * (z + tz);
            const int idx = b * H + h0 + hh;
            score[idx] = a;
            loss[idx] = fminf(l1, l2);
            normals[idx * 3 + 0] = x;
            normals[idx * 3 + 1] = y;
            normals[idx * 3 + 2] = z;
        }
    }
}

// ---------------------------------------------------------------------------
// Kernel 3: per batch finalize (r6 version): argmax (tie -> first), stable
// softmax(0.5*score), exp_loss, top_loss, pred. 256 threads, 2 hyps each.
// ---------------------------------------------------------------------------
__global__ __launch_bounds__(256) void finalize_kernel(
    const float* __restrict__ score,    // (B,H)
    const float* __restrict__ loss,     // (B,H)
    const float* __restrict__ normals,  // (B,H,3)
    float* __restrict__ out)            // exp_loss(B)|top_loss(B)|pred(3B)|gpts...
{
    const int b = blockIdx.x;
    const int tid = threadIdx.x;
    const int wave = tid >> 6;
    const int lane = tid & 63;

    __shared__ float sv[4]; __shared__ int sidx[4];
    __shared__ float ssw[4], sswl[4];
    __shared__ float s_max; __shared__ int s_maxi;

    const float* sc = score + b * H;
    const float* ls = loss + b * H;
    const float s0 = sc[tid], s1 = sc[tid + 256];

    float v; int vi;
    if (s1 > s0) { v = s1; vi = tid + 256; } else { v = s0; vi = tid; }
    #pragma unroll
    for (int off = 32; off; off >>= 1) {
        const float v2 = __shfl_xor(v, off);
        const int i2 = __shfl_xor(vi, off);
        if (v2 > v || (v2 == v && i2 < vi)) { v = v2; vi = i2; }
    }
    if (lane == 0) { sv[wave] = v; sidx[wave] = vi; }
    __syncthreads();

    if (tid == 0) {
        float bv = sv[0]; int bi = sidx[0];
        #pragma unroll
        for (int k = 1; k < 4; ++k) {
            if (sv[k] > bv || (sv[k] == bv && sidx[k] < bi)) { bv = sv[k]; bi = sidx[k]; }
        }
        s_max = bv; s_maxi = bi;
    }
    __syncthreads();

    const float m = s_max;
    const float w0 = __expf(0.5f * (s0 - m)), w1 = __expf(0.5f * (s1 - m));
    float tw = w0 + w1;
    float twl = w0 * ls[tid] + w1 * ls[tid + 256];
    #pragma unroll
    for (int off = 32; off; off >>= 1) {
        tw += __shfl_xor(tw, off);
        twl += __shfl_xor(twl, off);
    }
    if (lane == 0) { ssw[wave] = tw; sswl[wave] = twl; }
    __syncthreads();

    if (tid == 0) {
        const float TW = ssw[0] + ssw[1] + ssw[2] + ssw[3];
        const float TWL = sswl[0] + sswl[1] + sswl[2] + sswl[3];
        const int mi = s_maxi;
        out[b] = TWL / TW;                               // exp_loss
        out[B + b] = ls[mi];                             // top_loss
        out[2 * B + b * 3 + 0] = normals[((size_t)b * H + mi) * 3 + 0];
        out[2 * B + b * 3 + 1] = normals[((size_t)b * H + mi) * 3 + 1];
        out[2 * B + b * 3 + 2] = normals[((size_t)b * H + mi) * 3 + 2];
    }
}

// ---------------------------------------------------------------------------
extern "C" void kernel_launch(void* const* d_in, const int* in_sizes, int n_in,
                              void* d_out, int out_size, void* d_ws, size_t ws_size,
                              hipStream_t stream) {
    const float* pts       = (const float*)d_in[0];  // (B,3,N)
    const float* target    = (const float*)d_in[1];  // (B,3)
    const float* pt_weight = (const float*)d_in[2];  // (B,N)
    const int*   sel_idx   = (const int*)d_in[3];    // (B,H,3)

    float* out = (float*)d_out;
    // layout: exp_loss[B] | top_loss[B] | pred[B*3] | gpts[B*G*3]
    float* out_gpts = out + 5 * B;

    float* ws      = (float*)d_ws;
    float* score   = ws;                      // B*H
    float* loss    = ws + B * H;              // B*H
    float* normals = ws + 2 * B * H;          // B*H*3

    topk_gather_kernel<<<B * TKB, 1024, 0, stream>>>(pts, pt_weight, out_gpts);
    plane_score_kernel<<<B * 16, 256, 0, stream>>>(pts, target, sel_idx, out_gpts,
                                                   score, loss, normals);
    finalize_kernel<<<B, 256, 0, stream>>>(score, loss, normals, out);
}